// Round 1
// baseline (22298.486 us; speedup 1.0000x reference)
//
#include <hip/hip_runtime.h>
#include <math.h>

// Persistent-kernel LSTM: H=2048, SEQ=4096, fp32 (no fp32 MFMA -> vector ALU).
// 256 WGs x 512 thr, 1 WG/CU. Wave w of WG g owns hidden unit k=g*8+w; each
// lane holds 4 gate-rows x 32 cols of W_hh (128 floats).
//
// Cross-step exchange v3: DATA-AS-FLAG sentinel ring (no flags, 1 barrier/step).
//   ring[NS=4][2048] floats in d_ws. |h| < 1 strictly, so qNaN bits
//   0x7fc00000 is an unreachable sentinel. Producers store h directly
//   (relaxed agent -> LLC); every consumer thread polls ITS OWN 4 values
//   until != sentinel -- the poll IS the staging load. Slot s is:
//   produced at t=s(+4j), consumed at t=s+1, sentinel-reset at t=s+2
//   (safe: poll success of h_{t-1} proves all WGs consumed slot (t+2)&3;
//   reset store is vmcnt-drained by the resetter's next __syncthreads,
//   which happens before it publishes again -> no stale-epoch reads).
// This removes the flag store trip, the flag poll trip, and the post-poll
// data reload of the old protocol (~2 LLC round-trips off the serial path),
// and drops from 3 barriers/step to 1.
// First poll sweep for step t+1 issues right after publishing h_t, hiding
// one LLC latency under the off-path y computation.
// d_ws usage: 32 KB.

#define HDIM 2048
#define SEQ 4096
#define NWG 256
#define TPB 512
#define NS 4                    // ring slots (power of 2, >= 4)
#define SENTB 0x7fc00000u       // qNaN bits: impossible for |h|<1
#define GUARD_MAX 3000          // protocol-failure escape (no hang)

__device__ __forceinline__ float sigmoidf_(float x) {
  return __builtin_amdgcn_rcpf(1.0f + __expf(-x));
}
__device__ __forceinline__ float tanh_(float x) {
  float e = __expf(-2.0f * fabsf(x));
  float r = (1.0f - e) * __builtin_amdgcn_rcpf(1.0f + e);
  return copysignf(r, x);
}

// slots 0..NS-2 <- sentinel; slot NS-1 <- 0.0f (h_{-1} = 0, consumed at t=0)
__global__ void lstm_init(unsigned* ring) {
  const int i = blockIdx.x * 256 + threadIdx.x;   // 32 blocks x 256 = 8192
  ring[i] = (i >= (NS - 1) * HDIM) ? 0u : SENTB;
}

__global__ __launch_bounds__(TPB, 2) void lstm_persist(
    const float* __restrict__ x, const float* __restrict__ w_ih,
    const float* __restrict__ w_hh, const float* __restrict__ b_ih,
    const float* __restrict__ b_hh, const float* __restrict__ w_out,
    const float* __restrict__ b_out, float* __restrict__ out,
    unsigned* __restrict__ ring)
{
  const int wg   = blockIdx.x;
  const int tid  = threadIdx.x;
  const int wave = tid >> 6;
  const int lane = tid & 63;
  const int k    = wg * 8 + wave;   // this wave's hidden unit

  __shared__ float xs[SEQ];        // 16 KB
  __shared__ float hs[2][HDIM];    // 16 KB, double-buffered
  __shared__ float wys[2][8];      // per-wave y partials, double-buffered

  // ---- one-time: weights into registers ----
  // rows g=0..3 (gates i,f,g,o of unit k): row = k + g*HDIM
  // cols per lane: {256*j + 4*lane + q}, j=0..7, q=0..3  -> 32 float4
  float4 W[32];
  float wx[4], bb[4];
  #pragma unroll
  for (int g = 0; g < 4; ++g) {
    const int row = k + g * HDIM;
    const float* rp = w_hh + (size_t)row * HDIM + lane * 4;
    #pragma unroll
    for (int j = 0; j < 8; ++j)
      W[g * 8 + j] = *(const float4*)(rp + j * 256);
    wx[g] = w_ih[row];
    bb[g] = b_ih[row] + b_hh[row];
  }
  float wo[4];
  #pragma unroll
  for (int q = 0; q < 4; ++q) wo[q] = w_out[tid + TPB * q];
  const float bout = b_out[0];

  for (int i = tid; i < SEQ; i += TPB) xs[i] = x[i];

  float cc = 0.f, hh = 0.f;

  // ---- issue first poll: slot NS-1 holds h_{-1} = 0 (ready immediately) ----
  const unsigned* poll_p = ring + (size_t)(NS - 1) * HDIM + tid;
  unsigned u[4];
  #pragma unroll
  for (int q = 0; q < 4; ++q)
    u[q] = __hip_atomic_load(poll_p + q * TPB, __ATOMIC_RELAXED,
                             __HIP_MEMORY_SCOPE_AGENT);
  __syncthreads();

  for (int t = 0; t < SEQ; ++t) {
    const int par = t & 1;

    // ---- finish poll of slot s_{t-1}: every thread spins on its 4 values ----
    for (int guard = 0;;) {
      const int miss = (u[0] == SENTB) | (u[1] == SENTB) |
                       (u[2] == SENTB) | (u[3] == SENTB);
      if (!__any(miss) || ++guard > GUARD_MAX) break;
      #pragma unroll
      for (int q = 0; q < 4; ++q)
        if (u[q] == SENTB)
          u[q] = __hip_atomic_load(poll_p + q * TPB, __ATOMIC_RELAXED,
                                   __HIP_MEMORY_SCOPE_AGENT);
      __builtin_amdgcn_s_sleep(1);   // throttle the sweep rate a bit
    }
    float hv[4];
    #pragma unroll
    for (int q = 0; q < 4; ++q) {
      hv[q] = __uint_as_float(u[q]);
      hs[par][tid + TPB * q] = hv[q];
    }
    __syncthreads();  // B: hs[par] ready; drains last step's stores (vmcnt 0)

    // ---- off-path: sentinel-reset slot (t+2)&3 for its next epoch ----
    // (poll success of h_{t-1} proves every WG consumed slot (t+2)&3)
    if (t >= 1 && lane == 0)
      __hip_atomic_store(ring + (size_t)((t + NS - 2) & (NS - 1)) * HDIM + k,
                         SENTB, __ATOMIC_RELAXED, __HIP_MEMORY_SCOPE_AGENT);

    // ---- off-path: drain y_{t-2} (wys[par^1] written at step t-1) ----
    if (t >= 2 && wg == 0 && tid == 0)
      out[t - 2] = wys[par ^ 1][0] + wys[par ^ 1][1] + wys[par ^ 1][2] +
                   wys[par ^ 1][3] + wys[par ^ 1][4] + wys[par ^ 1][5] +
                   wys[par ^ 1][6] + wys[par ^ 1][7] + bout;

    // ---- z = W_hh @ h (per-lane partials over 32 columns) ----
    float acc[4] = {0.f, 0.f, 0.f, 0.f};
    #pragma unroll
    for (int j = 0; j < 8; ++j) {
      const float4 h4 = *(const float4*)&hs[par][j * 256 + lane * 4];
      #pragma unroll
      for (int g = 0; g < 4; ++g) {
        const float4 w = W[g * 8 + j];
        acc[g] = fmaf(w.x, h4.x, acc[g]);
        acc[g] = fmaf(w.y, h4.y, acc[g]);
        acc[g] = fmaf(w.z, h4.z, acc[g]);
        acc[g] = fmaf(w.w, h4.w, acc[g]);
      }
    }
    // ---- 16-shuffle reduction (was 24): fold xor32 first, pack gate pairs
    // into wave halves, 5 within-half stages, 1 cross-half gather ----
    const float a0 = acc[0] + __shfl_xor(acc[0], 32, 64);
    const float a1 = acc[1] + __shfl_xor(acc[1], 32, 64);
    const float a2 = acc[2] + __shfl_xor(acc[2], 32, 64);
    const float a3 = acc[3] + __shfl_xor(acc[3], 32, 64);
    const bool lohalf = (lane < 32);
    float s01 = lohalf ? a0 : a1;
    float s23 = lohalf ? a2 : a3;
    #pragma unroll
    for (int off = 16; off >= 1; off >>= 1) {
      s01 += __shfl_xor(s01, off, 64);
      s23 += __shfl_xor(s23, off, 64);
    }
    const float o01 = __shfl_xor(s01, 32, 64);
    const float o23 = __shfl_xor(s23, 32, 64);
    float z[4];
    z[0] = lohalf ? s01 : o01;
    z[1] = lohalf ? o01 : s01;
    z[2] = lohalf ? s23 : o23;
    z[3] = lohalf ? o23 : s23;

    const float xt = xs[t];
    #pragma unroll
    for (int g = 0; g < 4; ++g) z[g] = fmaf(xt, wx[g], z[g] + bb[g]);

    // ---- gates (lane-redundant, identical values) ----
    const float gi = sigmoidf_(z[0]), gf = sigmoidf_(z[1]);
    const float gg = tanh_(z[2]), go = sigmoidf_(z[3]);
    cc = gf * cc + gi * gg;
    hh = go * tanh_(cc);

    // ---- publish h_t: data IS the flag ----
    if (lane == 0)
      __hip_atomic_store(ring + (size_t)(t & (NS - 1)) * HDIM + k,
                         __float_as_uint(hh), __ATOMIC_RELAXED,
                         __HIP_MEMORY_SCOPE_AGENT);

    // ---- issue first sweep of next step's poll (hides one LLC latency
    //      under the y computation below) ----
    if (t + 1 < SEQ) {
      poll_p = ring + (size_t)(t & (NS - 1)) * HDIM + tid;
      #pragma unroll
      for (int q = 0; q < 4; ++q)
        u[q] = __hip_atomic_load(poll_p + q * TPB, __ATOMIC_RELAXED,
                                 __HIP_MEMORY_SCOPE_AGENT);
    }

    // ---- off-path: y_{t-1} partial from hv (h_{t-1}) ----
    float sy = 0.f;
    #pragma unroll
    for (int q = 0; q < 4; ++q) sy = fmaf(wo[q], hv[q], sy);
    #pragma unroll
    for (int off = 32; off >= 1; off >>= 1) sy += __shfl_xor(sy, off, 64);
    if (lane == 0) wys[par][wave] = sy;
  }

  // ---- epilogue ----
  __syncthreads();  // wys[1] (y partial for h_{SEQ-2}) complete
  if (wg == 0 && tid == 0)
    out[SEQ - 2] = wys[1][0] + wys[1][1] + wys[1][2] + wys[1][3] + wys[1][4] +
                   wys[1][5] + wys[1][6] + wys[1][7] + bout;

  // final h, c
  if (lane == 0) {
    out[SEQ + k] = hh;
    out[SEQ + HDIM + k] = cc;
  }

  if (wg == 0) {
    // y_{SEQ-1} = w_out . h_{SEQ-1}: poll slot (SEQ-1)&3 (all producers have
    // published; their stores drain at their epilogue barrier at the latest)
    const unsigned* pp = ring + (size_t)((SEQ - 1) & (NS - 1)) * HDIM + tid;
    unsigned v[4];
    #pragma unroll
    for (int q = 0; q < 4; ++q)
      v[q] = __hip_atomic_load(pp + q * TPB, __ATOMIC_RELAXED,
                               __HIP_MEMORY_SCOPE_AGENT);
    for (int guard = 0;;) {
      const int miss = (v[0] == SENTB) | (v[1] == SENTB) |
                       (v[2] == SENTB) | (v[3] == SENTB);
      if (!__any(miss) || ++guard > GUARD_MAX) break;
      #pragma unroll
      for (int q = 0; q < 4; ++q)
        if (v[q] == SENTB)
          v[q] = __hip_atomic_load(pp + q * TPB, __ATOMIC_RELAXED,
                                   __HIP_MEMORY_SCOPE_AGENT);
      __builtin_amdgcn_s_sleep(1);
    }
    float sy = 0.f;
    #pragma unroll
    for (int q = 0; q < 4; ++q)
      sy = fmaf(wo[q], __uint_as_float(v[q]), sy);
    #pragma unroll
    for (int off = 32; off >= 1; off >>= 1) sy += __shfl_xor(sy, off, 64);
    if (lane == 0) wys[0][wave] = sy;
    __syncthreads();
    if (tid == 0)
      out[SEQ - 1] = wys[0][0] + wys[0][1] + wys[0][2] + wys[0][3] +
                     wys[0][4] + wys[0][5] + wys[0][6] + wys[0][7] + bout;
  }
}

extern "C" void kernel_launch(void* const* d_in, const int* in_sizes, int n_in,
                              void* d_out, int out_size, void* d_ws, size_t ws_size,
                              hipStream_t stream) {
  const float* x     = (const float*)d_in[0];
  const float* w_ih  = (const float*)d_in[1];
  const float* w_hh  = (const float*)d_in[2];
  const float* b_ih  = (const float*)d_in[3];
  const float* b_hh  = (const float*)d_in[4];
  const float* w_out = (const float*)d_in[5];
  const float* b_out = (const float*)d_in[6];
  float* out = (float*)d_out;

  // ws layout: [0, 32KB): ring[4][2048] float (sentinel-coded h slots)
  unsigned* ring = (unsigned*)d_ws;

  lstm_init<<<32, 256, 0, stream>>>(ring);
  lstm_persist<<<NWG, TPB, 0, stream>>>(x, w_ih, w_hh, b_ih, b_hh, w_out,
                                        b_out, out, ring);
}